// Round 18
// baseline (519.846 us; speedup 1.0000x reference)
//
#include <hip/hip_runtime.h>
#include <hip/hip_fp16.h>

// N=100000 nodes, E=1000000 edges, D_IN=16, H=2, C=64.
// 3x (GAT -> BN -> ReLU), then MLP head -> (logits, value) concat in d_out.
// R17 structure (best: 509us) + R18: atomic-free CSR build (per-block
// histogram rows + precomputed scatter bases) and slice-write bn_stats
// (no memsets, no global atomics).

__device__ __forceinline__ float leaky(float x) { return x > 0.f ? x : 0.2f * x; }

#define BCAP 4096   // max edges per 256-dst bucket (mean ~2560)
#define EB 8192     // edges per CSR-build block
#define NSL 256     // bn_stats slices

// ---------------- CSR build (atomic-free global phase) ----------------
// per-block bucket histogram -> bhist[b*512 + bk]
__global__ __launch_bounds__(256) void bucket_count(
    const int* __restrict__ dst, int* __restrict__ bhist, int E) {
  __shared__ int cnt[512];
  int t = threadIdx.x;
  cnt[t] = 0; cnt[t + 256] = 0;
  __syncthreads();
  int beg = blockIdx.x * EB, end = min(E, beg + EB);
  for (int e = beg + t; e < end; e += 256)
    atomicAdd(&cnt[dst[e] >> 8], 1);
  __syncthreads();
  bhist[blockIdx.x * 512 + t] = cnt[t];
  bhist[blockIdx.x * 512 + t + 256] = cnt[t + 256];
}

// bucket totals -> exclusive scan (boff) -> per-block run bases (bbase)
__global__ void bucket_scan2(const int* __restrict__ bhist, int* __restrict__ bbase,
                             int* __restrict__ boff, int nb) {
  __shared__ int temp[512];
  int t = threadIdx.x;  // 512 threads, one bucket each
  int tot = 0;
  for (int b = 0; b < nb; b++) tot += bhist[b * 512 + t];
  temp[t] = tot;
  __syncthreads();
  for (int off = 1; off < 512; off <<= 1) {
    int add = (t >= off) ? temp[t - off] : 0;
    __syncthreads();
    temp[t] += add;
    __syncthreads();
  }
  int excl = temp[t] - tot;
  boff[t] = excl;
  int run = excl;
  for (int b = 0; b < nb; b++) {
    bbase[b * 512 + t] = run;
    run += bhist[b * 512 + t];
  }
}

// scatter into bucket-binned ebuf using precomputed bases (LDS cursors only)
__global__ __launch_bounds__(256) void bin_scatter2(
    const int* __restrict__ src, const int* __restrict__ dst,
    const int* __restrict__ bbase, int2* __restrict__ ebuf, int E) {
  __shared__ int cur[512];
  int t = threadIdx.x;
  cur[t] = bbase[blockIdx.x * 512 + t];
  cur[t + 256] = bbase[blockIdx.x * 512 + t + 256];
  __syncthreads();
  int beg = blockIdx.x * EB, end = min(E, beg + EB);
  for (int e = beg + t; e < end; e += 256) {
    int d = dst[e];
    int pos = atomicAdd(&cur[d >> 8], 1);
    ebuf[pos] = make_int2(src[e], d);
  }
}

// one block per bucket: LDS counting sort by dst, emit row_ptr + sorted col2
__global__ __launch_bounds__(256) void bucket_sort(
    const int2* __restrict__ ebuf, const int* __restrict__ boff,
    int2* __restrict__ col2, int* __restrict__ row_ptr, int E, int n, int nbk) {
  __shared__ int2 eds[BCAP];
  __shared__ int dcnt[256];
  __shared__ int dbase[256];
  __shared__ int dexcl[256];
  int b = blockIdx.x, t = threadIdx.x;
  int S = boff[b];
  int Eend = (b + 1 < nbk) ? boff[b + 1] : E;
  int cnt = min(Eend - S, BCAP);
  for (int i = t; i < cnt; i += 256) eds[i] = ebuf[S + i];
  dcnt[t] = 0;
  __syncthreads();
  for (int i = t; i < cnt; i += 256) atomicAdd(&dcnt[eds[i].y & 255], 1);
  __syncthreads();
  int v = dcnt[t];
  dbase[t] = v;
  __syncthreads();
  for (int off = 1; off < 256; off <<= 1) {
    int add = (t >= off) ? dbase[t - off] : 0;
    __syncthreads();
    dbase[t] += add;
    __syncthreads();
  }
  int excl = dbase[t] - v;
  int d = (b << 8) + t;
  if (d < n) row_ptr[d] = S + excl;
  if (b == nbk - 1 && t == 0) row_ptr[n] = E;
  dcnt[t] = 0;  // reuse as per-dst cursor
  dexcl[t] = excl;
  __syncthreads();
  for (int i = t; i < cnt; i += 256) {
    int2 e = eds[i];
    int dl = e.y & 255;
    int off = atomicAdd(&dcnt[dl], 1);
    col2[S + dexcl[dl] + off] = e;
  }
}

// ---------------- BN stats (vectorized, slice writes) + finalize ----------
// float4 grid-stride; each block writes its partial to stats[block*128 + ...]
__global__ __launch_bounds__(256) void bn_stats(const float* __restrict__ h,
                                                float* __restrict__ stats, int n) {
  __shared__ float ssum[64], ssq[64];
  int t = threadIdx.x;
  if (t < 64) { ssum[t] = 0.f; ssq[t] = 0.f; }
  __syncthreads();
  const float4* h4 = (const float4*)h;
  size_t total4 = (size_t)n * 16;
  size_t stride = (size_t)gridDim.x * blockDim.x;   // multiple of 16
  int cbase = ((int)(((size_t)blockIdx.x * blockDim.x + t) & 15)) * 4;
  float s0 = 0.f, s1 = 0.f, s2 = 0.f, s3 = 0.f;
  float q0 = 0.f, q1 = 0.f, q2 = 0.f, q3 = 0.f;
  for (size_t i = (size_t)blockIdx.x * blockDim.x + t; i < total4; i += stride) {
    float4 v = h4[i];
    s0 += v.x; q0 = fmaf(v.x, v.x, q0);
    s1 += v.y; q1 = fmaf(v.y, v.y, q1);
    s2 += v.z; q2 = fmaf(v.z, v.z, q2);
    s3 += v.w; q3 = fmaf(v.w, v.w, q3);
  }
  atomicAdd(&ssum[cbase + 0], s0); atomicAdd(&ssq[cbase + 0], q0);
  atomicAdd(&ssum[cbase + 1], s1); atomicAdd(&ssq[cbase + 1], q1);
  atomicAdd(&ssum[cbase + 2], s2); atomicAdd(&ssq[cbase + 2], q2);
  atomicAdd(&ssum[cbase + 3], s3); atomicAdd(&ssq[cbase + 3], q3);
  __syncthreads();
  if (t < 64) {
    stats[blockIdx.x * 128 + t] = ssum[t];
    stats[blockIdx.x * 128 + 64 + t] = ssq[t];
  }
}

// reduce NSL slices -> scsh (scale/shift). 128 threads: t<64 sums, else sumsq.
__global__ void bn_finalize(const float* __restrict__ stats, const float* __restrict__ g,
                            const float* __restrict__ be, float* __restrict__ scsh,
                            float inv_n) {
  __shared__ float red[128];
  int t = threadIdx.x;  // 128
  int c = t & 63;
  int off = (t >> 6) * 64;  // 0 = sum, 64 = sumsq
  float acc = 0.f;
  for (int b = 0; b < NSL; b++) acc += stats[b * 128 + off + c];
  red[t] = acc;
  __syncthreads();
  if (t < 64) {
    float mean = red[t] * inv_n;
    float var = red[64 + t] * inv_n - mean * mean;
    float sc = rsqrtf(var + 1e-5f) * g[t];
    scsh[t] = sc;
    scsh[64 + t] = be[t] - mean * sc;
  }
}

// ---------------- GAT projection: LDS-tiled GEMM, 64 nodes x 128 cols -------
// h = act @ W (BN+ReLU fused into A-staging when BN=true).
template <int K, bool BN>
__global__ __launch_bounds__(256) void gat_project_tiled(
    const float* __restrict__ act, const float* __restrict__ scsh,
    const float* __restrict__ W,
    const float* __restrict__ att_s, const float* __restrict__ att_d,
    __half2* __restrict__ hb, float* __restrict__ as_,
    float* __restrict__ ad_, int n) {
  constexpr int AST = K + 4;
  __shared__ float aS[64 * AST];
  __shared__ float wS[K * 128];
  __shared__ float attS[256];

  int t = threadIdx.x;
  int node0 = blockIdx.x * 64;
  int rows = min(64, n - node0);

  constexpr int AF4 = 64 * K / 4;
  for (int i = t; i < AF4; i += 256) {
    int r = i / (K / 4), kc = i % (K / 4);
    float4 v = make_float4(0.f, 0.f, 0.f, 0.f);
    if (r < rows) v = *(const float4*)&act[(size_t)(node0 + r) * K + kc * 4];
    if (BN) {
      float4 sc4 = *(const float4*)&scsh[kc * 4];
      float4 sh4 = *(const float4*)&scsh[64 + kc * 4];
      v.x = fmaxf(fmaf(v.x, sc4.x, sh4.x), 0.f);
      v.y = fmaxf(fmaf(v.y, sc4.y, sh4.y), 0.f);
      v.z = fmaxf(fmaf(v.z, sc4.z, sh4.z), 0.f);
      v.w = fmaxf(fmaf(v.w, sc4.w, sh4.w), 0.f);
    }
    *(float4*)&aS[r * AST + kc * 4] = v;
  }
  constexpr int WF4 = K * 32;
  for (int i = t; i < WF4; i += 256)
    *(float4*)&wS[i * 4] = *(const float4*)&W[i * 4];
  attS[t] = (t < 128) ? att_s[t] : att_d[t - 128];
  __syncthreads();

  int tc = t & 15, tr = t >> 4;
  int c0 = tc * 8, r0 = tr * 4;

  float acc[4][8] = {};
  for (int k = 0; k < K; k += 4) {
    float4 av[4];
    float4 wv[4][2];
#pragma unroll
    for (int i = 0; i < 4; i++) av[i] = *(const float4*)&aS[(r0 + i) * AST + k];
#pragma unroll
    for (int kk = 0; kk < 4; kk++) {
      wv[kk][0] = *(const float4*)&wS[(k + kk) * 128 + c0];
      wv[kk][1] = *(const float4*)&wS[(k + kk) * 128 + c0 + 4];
    }
#pragma unroll
    for (int i = 0; i < 4; i++) {
      const float* ai = (const float*)&av[i];
#pragma unroll
      for (int kk = 0; kk < 4; kk++) {
        const float* w0 = (const float*)&wv[kk][0];
        const float* w1 = (const float*)&wv[kk][1];
#pragma unroll
        for (int j = 0; j < 4; j++) {
          acc[i][j] = fmaf(ai[kk], w0[j], acc[i][j]);
          acc[i][4 + j] = fmaf(ai[kk], w1[j], acc[i][4 + j]);
        }
      }
    }
  }

#pragma unroll
  for (int i = 0; i < 4; i++) {
    int r = r0 + i;
    float psv = 0.f, pdv = 0.f;
#pragma unroll
    for (int j = 0; j < 8; j++) {
      psv = fmaf(acc[i][j], attS[c0 + j], psv);
      pdv = fmaf(acc[i][j], attS[128 + c0 + j], pdv);
    }
    psv += __shfl_xor(psv, 1); pdv += __shfl_xor(pdv, 1);
    psv += __shfl_xor(psv, 2); pdv += __shfl_xor(pdv, 2);
    psv += __shfl_xor(psv, 4); pdv += __shfl_xor(pdv, 4);
    if (r < rows) {
      size_t base = (size_t)(node0 + r) * 64 + (c0 >> 1);
      hb[base + 0] = __floats2half2_rn(acc[i][0], acc[i][1]);
      hb[base + 1] = __floats2half2_rn(acc[i][2], acc[i][3]);
      hb[base + 2] = __floats2half2_rn(acc[i][4], acc[i][5]);
      hb[base + 3] = __floats2half2_rn(acc[i][6], acc[i][7]);
      if (tc == 0 || tc == 8) {
        int head = tc >> 3;
        as_[(node0 + r) * 2 + head] = psv;
        ad_[(node0 + r) * 2 + head] = pdv;
      }
    }
  }
}

// ---------------- GAT aggregation: wave per node ----------------------------
// 4 edges/group, 16 lanes/edge (sub = lane>>4, q = lane&15, 8 ch/lane).
// Two groups pipelined per iteration. Inline scores (as_ L2-resident).
__device__ __forceinline__ void fma8(float* a, float my, uint4 raw) {
  float2 f;
  f = __half22float2(__builtin_bit_cast(__half2, raw.x)); a[0] = fmaf(my, f.x, a[0]); a[1] = fmaf(my, f.y, a[1]);
  f = __half22float2(__builtin_bit_cast(__half2, raw.y)); a[2] = fmaf(my, f.x, a[2]); a[3] = fmaf(my, f.y, a[3]);
  f = __half22float2(__builtin_bit_cast(__half2, raw.z)); a[4] = fmaf(my, f.x, a[4]); a[5] = fmaf(my, f.y, a[5]);
  f = __half22float2(__builtin_bit_cast(__half2, raw.w)); a[6] = fmaf(my, f.x, a[6]); a[7] = fmaf(my, f.y, a[7]);
}

__global__ __launch_bounds__(256) void gat_aggregate(
    const __half2* __restrict__ hb,
    const float* __restrict__ as_, const float* __restrict__ ad_,
    const int* __restrict__ row_ptr, const int2* __restrict__ col2,
    const float* __restrict__ bias, float* __restrict__ out, int n) {
  int wave = (int)((blockIdx.x * blockDim.x + threadIdx.x) >> 6);
  int lane = threadIdx.x & 63;
  if (wave >= n) return;
  int d = wave;
  int sub = lane >> 4, q = lane & 15;
  bool head1 = (q >= 8);
  int hidx = head1 ? 1 : 0;
  int beg = row_ptr[d], end = row_ptr[d + 1];
  const uint4* hb4 = (const uint4*)hb;   // 16 uint4 per node (256 B)

  float2 dv = *(const float2*)&ad_[d * 2];
  float ad_my = head1 ? dv.y : dv.x;

  float a[8] = {};
  float dpart = 0.f;

  if (sub == 0) {  // self-loop (not in CSR)
    float asv = as_[d * 2 + hidx];
    float my = __expf(leaky(asv + ad_my));
    uint4 raw = hb4[(size_t)d * 16 + q];
    fma8(a, my, raw);
    dpart = my;
  }

  int k = beg;
  for (; k + 7 < end; k += 8) {
    int kkA = k + sub, kkB = k + 4 + sub;
    int sA = col2[kkA].x;
    int sB = col2[kkB].x;
    float asA = as_[sA * 2 + hidx];
    float asB = as_[sB * 2 + hidx];
    uint4 rawA = hb4[(size_t)sA * 16 + q];
    uint4 rawB = hb4[(size_t)sB * 16 + q];
    float myA = __expf(leaky(asA + ad_my));
    float myB = __expf(leaky(asB + ad_my));
    fma8(a, myA, rawA);
    dpart += myA;
    fma8(a, myB, rawB);
    dpart += myB;
  }
  if (k + 3 < end) {
    int kk = k + sub;
    int s = col2[kk].x;
    float asv = as_[s * 2 + hidx];
    uint4 raw = hb4[(size_t)s * 16 + q];
    float my = __expf(leaky(asv + ad_my));
    fma8(a, my, raw);
    dpart += my;
    k += 4;
  }
  int rem = end - k;
  if (sub < rem) {
    int kk = k + sub;
    int s = col2[kk].x;
    float asv = as_[s * 2 + hidx];
    uint4 raw = hb4[(size_t)s * 16 + q];
    float my = __expf(leaky(asv + ad_my));
    fma8(a, my, raw);
    dpart += my;
  }

  // butterfly combine across the 4 sub groups (same q)
#pragma unroll
  for (int i = 0; i < 8; i++) a[i] += __shfl(a[i], lane ^ 16);
  dpart += __shfl(dpart, lane ^ 16);
#pragma unroll
  for (int i = 0; i < 8; i++) a[i] += __shfl(a[i], lane ^ 32);
  float dsum = dpart + __shfl(dpart, lane ^ 32);

  // head-1 values for lane q (<8) live at lane q+8 (same sub group)
  int src = (lane + 8) & 63;
  float b[8];
#pragma unroll
  for (int i = 0; i < 8; i++) b[i] = __shfl(a[i], src);
  float den1 = __shfl(dsum, src);
  if (lane < 8) {  // sub 0, q 0..7: output channels 8q..8q+7
    float r0 = 1.f / (dsum + 1e-16f), r1 = 1.f / (den1 + 1e-16f);
    float4 bl = *(const float4*)&bias[q * 8];
    float4 bh = *(const float4*)&bias[q * 8 + 4];
    float4 o0, o1;
    o0.x = 0.5f * (a[0] * r0 + b[0] * r1) + bl.x;
    o0.y = 0.5f * (a[1] * r0 + b[1] * r1) + bl.y;
    o0.z = 0.5f * (a[2] * r0 + b[2] * r1) + bl.z;
    o0.w = 0.5f * (a[3] * r0 + b[3] * r1) + bl.w;
    o1.x = 0.5f * (a[4] * r0 + b[4] * r1) + bh.x;
    o1.y = 0.5f * (a[5] * r0 + b[5] * r1) + bh.y;
    o1.z = 0.5f * (a[6] * r0 + b[6] * r1) + bh.z;
    o1.w = 0.5f * (a[7] * r0 + b[7] * r1) + bh.w;
    *(float4*)&out[(size_t)d * 64 + q * 8] = o0;
    *(float4*)&out[(size_t)d * 64 + q * 8 + 4] = o1;
  }
}

// ---------------- MLP head: fused tiled GEMM (64 nodes / block) --------------
// a1 staging applies BN(layer3 scsh)+ReLU to the raw aggregate output.
__global__ __launch_bounds__(256) void mlp_head_tiled(
    const float* __restrict__ h3raw, const float* __restrict__ scsh,
    const float* __restrict__ x,
    const float* __restrict__ mW1, const float* __restrict__ mb1,
    const float* __restrict__ mW2, const float* __restrict__ mb2,
    const float* __restrict__ pW, const float* __restrict__ pb,
    const float* __restrict__ vW, const float* __restrict__ vb,
    float* __restrict__ out, int n) {
  __shared__ float lds[13632];
  float* a1  = lds;           // 64*68 = 4352
  float* ctx = lds + 4352;    // 64*8  = 512
  float* a2  = lds + 4864;    // 64*68 = 4352
  float* w1  = lds + 9216;    // 69*64 = 4416
  float* w2  = lds;           // aliases a1 (dead after GEMM1)

  int t = threadIdx.x;
  int node0 = blockIdx.x * 64;
  int rows = min(64, n - node0);

#pragma unroll
  for (int i = 0; i < 4; i++) {
    int flat = t + i * 256;
    int r = flat >> 4, kc = flat & 15;
    float4 v = make_float4(0.f, 0.f, 0.f, 0.f);
    if (r < rows) v = *(const float4*)&h3raw[(size_t)(node0 + r) * 64 + kc * 4];
    float4 sc4 = *(const float4*)&scsh[kc * 4];
    float4 sh4 = *(const float4*)&scsh[64 + kc * 4];
    v.x = fmaxf(fmaf(v.x, sc4.x, sh4.x), 0.f);
    v.y = fmaxf(fmaf(v.y, sc4.y, sh4.y), 0.f);
    v.z = fmaxf(fmaf(v.z, sc4.z, sh4.z), 0.f);
    v.w = fmaxf(fmaf(v.w, sc4.w, sh4.w), 0.f);
    *(float4*)&a1[r * 68 + kc * 4] = v;
  }
  for (int i = t; i < 320; i += 256) {
    int r = i / 5, j = i % 5;
    ctx[r * 8 + j] = (r < rows) ? x[(size_t)(node0 + r) * 16 + 9 + j] : 0.f;
  }
#pragma unroll
  for (int i = 0; i < 5; i++) {
    int flat = t + i * 256;
    if (flat < 1104) *(float4*)&w1[flat * 4] = *(const float4*)&mW1[flat * 4];
  }
  __syncthreads();

  int tc = t & 15, tr = t >> 4;
  int c0 = tc * 4, r0 = tr * 4;

  float acc[4][4] = {};
  for (int k = 0; k < 64; k += 4) {
    float4 av[4], wv[4];
#pragma unroll
    for (int i = 0; i < 4; i++) av[i] = *(const float4*)&a1[(r0 + i) * 68 + k];
#pragma unroll
    for (int j = 0; j < 4; j++) wv[j] = *(const float4*)&w1[(k + j) * 64 + c0];
#pragma unroll
    for (int i = 0; i < 4; i++) {
      const float* ai = (const float*)&av[i];
#pragma unroll
      for (int kk = 0; kk < 4; kk++) {
        const float* wr = (const float*)&wv[kk];
        acc[i][0] = fmaf(ai[kk], wr[0], acc[i][0]);
        acc[i][1] = fmaf(ai[kk], wr[1], acc[i][1]);
        acc[i][2] = fmaf(ai[kk], wr[2], acc[i][2]);
        acc[i][3] = fmaf(ai[kk], wr[3], acc[i][3]);
      }
    }
  }
#pragma unroll
  for (int k = 64; k < 69; k++) {
    float4 wv = *(const float4*)&w1[k * 64 + c0];
    const float* wr = (const float*)&wv;
#pragma unroll
    for (int i = 0; i < 4; i++) {
      float a = ctx[(r0 + i) * 8 + (k - 64)];
      acc[i][0] = fmaf(a, wr[0], acc[i][0]);
      acc[i][1] = fmaf(a, wr[1], acc[i][1]);
      acc[i][2] = fmaf(a, wr[2], acc[i][2]);
      acc[i][3] = fmaf(a, wr[3], acc[i][3]);
    }
  }
  float b1v0 = mb1[c0], b1v1 = mb1[c0 + 1], b1v2 = mb1[c0 + 2], b1v3 = mb1[c0 + 3];
#pragma unroll
  for (int i = 0; i < 4; i++) {
    float4 t1;
    t1.x = fmaxf(acc[i][0] + b1v0, 0.f);
    t1.y = fmaxf(acc[i][1] + b1v1, 0.f);
    t1.z = fmaxf(acc[i][2] + b1v2, 0.f);
    t1.w = fmaxf(acc[i][3] + b1v3, 0.f);
    *(float4*)&a2[(r0 + i) * 68 + c0] = t1;
  }
  __syncthreads();

#pragma unroll
  for (int i = 0; i < 4; i++) {
    int flat = t + i * 256;
    *(float4*)&w2[flat * 4] = *(const float4*)&mW2[flat * 4];
  }
  __syncthreads();

  float acc2[4][4] = {};
  for (int k = 0; k < 64; k += 4) {
    float4 av[4], wv[4];
#pragma unroll
    for (int i = 0; i < 4; i++) av[i] = *(const float4*)&a2[(r0 + i) * 68 + k];
#pragma unroll
    for (int j = 0; j < 4; j++) wv[j] = *(const float4*)&w2[(k + j) * 64 + c0];
#pragma unroll
    for (int i = 0; i < 4; i++) {
      const float* ai = (const float*)&av[i];
#pragma unroll
      for (int kk = 0; kk < 4; kk++) {
        const float* wr = (const float*)&wv[kk];
        acc2[i][0] = fmaf(ai[kk], wr[0], acc2[i][0]);
        acc2[i][1] = fmaf(ai[kk], wr[1], acc2[i][1]);
        acc2[i][2] = fmaf(ai[kk], wr[2], acc2[i][2]);
        acc2[i][3] = fmaf(ai[kk], wr[3], acc2[i][3]);
      }
    }
  }

  float b2v[4], pwv[4], vwv[4];
#pragma unroll
  for (int j = 0; j < 4; j++) {
    b2v[j] = mb2[c0 + j];
    pwv[j] = pW[c0 + j];
    vwv[j] = vW[c0 + j];
  }
  float p[4], v[4];
#pragma unroll
  for (int i = 0; i < 4; i++) {
    float ps = 0.f, vs = 0.f;
#pragma unroll
    for (int j = 0; j < 4; j++) {
      float u = acc2[i][j] + b2v[j];
      ps = fmaf(u, pwv[j], ps);
      vs = fmaf(u, vwv[j], vs);
    }
    p[i] = ps; v[i] = vs;
  }
#pragma unroll
  for (int off = 1; off < 16; off <<= 1) {
#pragma unroll
    for (int i = 0; i < 4; i++) {
      p[i] += __shfl_xor(p[i], off);
      v[i] += __shfl_xor(v[i], off);
    }
  }
  if (tc == 0) {
    float pbs = pb[0], vbs = vb[0];
#pragma unroll
    for (int i = 0; i < 4; i++) {
      int r = r0 + i;
      if (r < rows) {
        out[node0 + r] = p[i] + pbs;
        out[n + node0 + r] = v[i] + vbs;
      }
    }
  }
}

extern "C" void kernel_launch(void* const* d_in, const int* in_sizes, int n_in,
                              void* d_out, int out_size, void* d_ws, size_t ws_size,
                              hipStream_t stream) {
  const float* x = (const float*)d_in[0];
  const int* ei = (const int*)d_in[1];
  const float* W[3]  = {(const float*)d_in[2],  (const float*)d_in[8],  (const float*)d_in[14]};
  const float* AS[3] = {(const float*)d_in[3],  (const float*)d_in[9],  (const float*)d_in[15]};
  const float* AD[3] = {(const float*)d_in[4],  (const float*)d_in[10], (const float*)d_in[16]};
  const float* B[3]  = {(const float*)d_in[5],  (const float*)d_in[11], (const float*)d_in[17]};
  const float* G[3]  = {(const float*)d_in[6],  (const float*)d_in[12], (const float*)d_in[18]};
  const float* BE[3] = {(const float*)d_in[7],  (const float*)d_in[13], (const float*)d_in[19]};
  const float* mW1 = (const float*)d_in[20];
  const float* mb1 = (const float*)d_in[21];
  const float* mW2 = (const float*)d_in[22];
  const float* mb2 = (const float*)d_in[23];
  const float* pW  = (const float*)d_in[24];
  const float* pb  = (const float*)d_in[25];
  const float* vW  = (const float*)d_in[26];
  const float* vb  = (const float*)d_in[27];

  const int N = in_sizes[0] / 16;
  const int E = in_sizes[1] / 2;
  const int* srcp = ei;
  const int* dstp = ei + E;

  const int nb = (E + EB - 1) / EB;          // CSR-build blocks (123)
  const int nbk = (N + 255) >> 8;            // 256-dst buckets (391)
  const float inv_n = 1.0f / (float)N;

  // workspace carve-up (~72 MB)
  float* bufB  = (float*)d_ws;               // N*64  raw aggregate output
  float* hbuf  = bufB + (size_t)N * 64;      // N*64 half2 region (N*64 f32 bytes)
  float* as_   = hbuf + (size_t)N * 64;      // N*2
  float* ad_   = as_ + (size_t)N * 2;        // N*2
  float* stats = ad_ + (size_t)N * 2;        // NSL*128
  float* scsh  = stats + NSL * 128;          // 128
  int* row_ptr = (int*)(scsh + 128);         // N+1
  int* bhist   = row_ptr + (N + 1);          // 128*512
  int* bbase   = bhist + 128 * 512;          // 128*512
  int* boff    = bbase + 128 * 512;          // 512
  int2* col2   = (int2*)(boff + 512);        // E int2 (sorted CSR)
  int2* ebuf   = col2 + E;                   // E int2 (staging)
  __half2* hb  = (__half2*)hbuf;

  // ---- CSR build: binned counting sort, atomic-free global phase
  bucket_count<<<nb, 256, 0, stream>>>(dstp, bhist, E);
  bucket_scan2<<<1, 512, 0, stream>>>(bhist, bbase, boff, nb);
  bin_scatter2<<<nb, 256, 0, stream>>>(srcp, dstp, bbase, ebuf, E);
  bucket_sort<<<nbk, 256, 0, stream>>>(ebuf, boff, col2, row_ptr, E, N, nbk);

  const int tiles = (N + 63) / 64;

  // ---- 3 GAT layers (BN+ReLU fused into the next consumer via scsh)
  for (int l = 0; l < 3; l++) {
    if (l == 0)
      gat_project_tiled<16, false><<<tiles, 256, 0, stream>>>(x, scsh, W[l], AS[l], AD[l],
                                                              hb, as_, ad_, N);
    else
      gat_project_tiled<64, true><<<tiles, 256, 0, stream>>>(bufB, scsh, W[l], AS[l], AD[l],
                                                             hb, as_, ad_, N);
    gat_aggregate<<<(N + 3) / 4, 256, 0, stream>>>(hb, as_, ad_, row_ptr, col2,
                                                   B[l], bufB, N);
    bn_stats<<<NSL, 256, 0, stream>>>(bufB, stats, N);
    bn_finalize<<<1, 128, 0, stream>>>(stats, G[l], BE[l], scsh, inv_n);
  }

  // ---- MLP head -> (logits, value); applies layer-3 BN+ReLU to bufB
  mlp_head_tiled<<<tiles, 256, 0, stream>>>(bufB, scsh, x, mW1, mb1, mW2, mb2,
                                            pW, pb, vW, vb, (float*)d_out, N);
}

// Round 19
// 505.114 us; speedup vs baseline: 1.0292x; 1.0292x over previous
//
#include <hip/hip_runtime.h>
#include <hip/hip_fp16.h>

// N=100000 nodes, E=1000000 edges, D_IN=16, H=2, C=64.
// 3x (GAT -> BN -> ReLU), then MLP head -> (logits, value) concat in d_out.
// R17 structure (best: 509us): hbuf fp16; aggregation 4 edges/group,
// 16 lanes/edge, 2 groups pipelined, inline scores; BN apply fused into
// consumers via scsh[128]; R17 CSR build (global-atomic hist/scatter —
// R18's "atomic-free" build regressed); slice-write bn_stats (no memsets).

__device__ __forceinline__ float leaky(float x) { return x > 0.f ? x : 0.2f * x; }

#define BCAP 4096  // max edges per 256-dst bucket (mean ~2560)
#define NSL 256    // bn_stats slices

// ---------------- CSR build ----------------
__global__ void bucket_hist(const int* __restrict__ dst, int* __restrict__ bcnt, int E) {
  __shared__ int cnt[512];
  int t = threadIdx.x;
  cnt[t] = 0; cnt[t + 256] = 0;
  __syncthreads();
  for (int e = blockIdx.x * blockDim.x + t; e < E; e += gridDim.x * blockDim.x)
    atomicAdd(&cnt[dst[e] >> 8], 1);
  __syncthreads();
  for (int i = t; i < 512; i += 256)
    if (cnt[i]) atomicAdd(&bcnt[i], cnt[i]);
}

__global__ void bucket_scan(const int* __restrict__ bcnt, int* __restrict__ boff,
                            int* __restrict__ bcur, int nbk) {
  __shared__ int temp[512];
  int t = threadIdx.x;  // 512 threads
  int v = (t < nbk) ? bcnt[t] : 0;
  temp[t] = v;
  __syncthreads();
  for (int off = 1; off < 512; off <<= 1) {
    int add = (t >= off) ? temp[t - off] : 0;
    __syncthreads();
    temp[t] += add;
    __syncthreads();
  }
  if (t < nbk) {
    int ex = temp[t] - v;
    boff[t] = ex;
    bcur[t] = ex;
  }
}

__global__ __launch_bounds__(256) void bin_scatter(
    const int* __restrict__ src, const int* __restrict__ dst,
    int* __restrict__ bcur, int2* __restrict__ ebuf, int E) {
  __shared__ int cnt[512];
  __shared__ int base[512];
  int t = threadIdx.x;
  int beg = blockIdx.x * 8192;
  int end = min(E, beg + 8192);
  cnt[t] = 0; cnt[t + 256] = 0;
  __syncthreads();
  for (int e = beg + t; e < end; e += 256)
    atomicAdd(&cnt[dst[e] >> 8], 1);
  __syncthreads();
  for (int i = t; i < 512; i += 256) {
    base[i] = cnt[i] ? atomicAdd(&bcur[i], cnt[i]) : 0;
    cnt[i] = 0;  // reuse as within-run cursor
  }
  __syncthreads();
  for (int e = beg + t; e < end; e += 256) {
    int d = dst[e];
    int bk = d >> 8;
    int off = atomicAdd(&cnt[bk], 1);
    ebuf[base[bk] + off] = make_int2(src[e], d);
  }
}

__global__ __launch_bounds__(256) void bucket_sort(
    const int2* __restrict__ ebuf, const int* __restrict__ boff,
    int2* __restrict__ col2, int* __restrict__ row_ptr, int E, int n, int nbk) {
  __shared__ int2 eds[BCAP];
  __shared__ int dcnt[256];
  __shared__ int dbase[256];
  __shared__ int dexcl[256];
  int b = blockIdx.x, t = threadIdx.x;
  int S = boff[b];
  int Eend = (b + 1 < nbk) ? boff[b + 1] : E;
  int cnt = min(Eend - S, BCAP);
  for (int i = t; i < cnt; i += 256) eds[i] = ebuf[S + i];
  dcnt[t] = 0;
  __syncthreads();
  for (int i = t; i < cnt; i += 256) atomicAdd(&dcnt[eds[i].y & 255], 1);
  __syncthreads();
  int v = dcnt[t];
  dbase[t] = v;
  __syncthreads();
  for (int off = 1; off < 256; off <<= 1) {
    int add = (t >= off) ? dbase[t - off] : 0;
    __syncthreads();
    dbase[t] += add;
    __syncthreads();
  }
  int excl = dbase[t] - v;
  int d = (b << 8) + t;
  if (d < n) row_ptr[d] = S + excl;
  if (b == nbk - 1 && t == 0) row_ptr[n] = E;
  dcnt[t] = 0;  // reuse as per-dst cursor
  dexcl[t] = excl;
  __syncthreads();
  for (int i = t; i < cnt; i += 256) {
    int2 e = eds[i];
    int dl = e.y & 255;
    int off = atomicAdd(&dcnt[dl], 1);
    col2[S + dexcl[dl] + off] = e;
  }
}

// ---------------- BN stats (vectorized, slice writes) + finalize ----------
__global__ __launch_bounds__(256) void bn_stats(const float* __restrict__ h,
                                                float* __restrict__ stats, int n) {
  __shared__ float ssum[64], ssq[64];
  int t = threadIdx.x;
  if (t < 64) { ssum[t] = 0.f; ssq[t] = 0.f; }
  __syncthreads();
  const float4* h4 = (const float4*)h;
  size_t total4 = (size_t)n * 16;
  size_t stride = (size_t)gridDim.x * blockDim.x;   // multiple of 16
  int cbase = ((int)(((size_t)blockIdx.x * blockDim.x + t) & 15)) * 4;
  float s0 = 0.f, s1 = 0.f, s2 = 0.f, s3 = 0.f;
  float q0 = 0.f, q1 = 0.f, q2 = 0.f, q3 = 0.f;
  for (size_t i = (size_t)blockIdx.x * blockDim.x + t; i < total4; i += stride) {
    float4 v = h4[i];
    s0 += v.x; q0 = fmaf(v.x, v.x, q0);
    s1 += v.y; q1 = fmaf(v.y, v.y, q1);
    s2 += v.z; q2 = fmaf(v.z, v.z, q2);
    s3 += v.w; q3 = fmaf(v.w, v.w, q3);
  }
  atomicAdd(&ssum[cbase + 0], s0); atomicAdd(&ssq[cbase + 0], q0);
  atomicAdd(&ssum[cbase + 1], s1); atomicAdd(&ssq[cbase + 1], q1);
  atomicAdd(&ssum[cbase + 2], s2); atomicAdd(&ssq[cbase + 2], q2);
  atomicAdd(&ssum[cbase + 3], s3); atomicAdd(&ssq[cbase + 3], q3);
  __syncthreads();
  if (t < 64) {
    stats[blockIdx.x * 128 + t] = ssum[t];
    stats[blockIdx.x * 128 + 64 + t] = ssq[t];
  }
}

// reduce NSL slices -> scsh (scale/shift). 128 threads: t<64 sums, else sumsq.
__global__ void bn_finalize(const float* __restrict__ stats, const float* __restrict__ g,
                            const float* __restrict__ be, float* __restrict__ scsh,
                            float inv_n) {
  __shared__ float red[128];
  int t = threadIdx.x;  // 128
  int c = t & 63;
  int off = (t >> 6) * 64;  // 0 = sum, 64 = sumsq
  float acc = 0.f;
  for (int b = 0; b < NSL; b++) acc += stats[b * 128 + off + c];
  red[t] = acc;
  __syncthreads();
  if (t < 64) {
    float mean = red[t] * inv_n;
    float var = red[64 + t] * inv_n - mean * mean;
    float sc = rsqrtf(var + 1e-5f) * g[t];
    scsh[t] = sc;
    scsh[64 + t] = be[t] - mean * sc;
  }
}

// ---------------- GAT projection: LDS-tiled GEMM, 64 nodes x 128 cols -------
// h = act @ W (BN+ReLU fused into A-staging when BN=true).
template <int K, bool BN>
__global__ __launch_bounds__(256) void gat_project_tiled(
    const float* __restrict__ act, const float* __restrict__ scsh,
    const float* __restrict__ W,
    const float* __restrict__ att_s, const float* __restrict__ att_d,
    __half2* __restrict__ hb, float* __restrict__ as_,
    float* __restrict__ ad_, int n) {
  constexpr int AST = K + 4;
  __shared__ float aS[64 * AST];
  __shared__ float wS[K * 128];
  __shared__ float attS[256];

  int t = threadIdx.x;
  int node0 = blockIdx.x * 64;
  int rows = min(64, n - node0);

  constexpr int AF4 = 64 * K / 4;
  for (int i = t; i < AF4; i += 256) {
    int r = i / (K / 4), kc = i % (K / 4);
    float4 v = make_float4(0.f, 0.f, 0.f, 0.f);
    if (r < rows) v = *(const float4*)&act[(size_t)(node0 + r) * K + kc * 4];
    if (BN) {
      float4 sc4 = *(const float4*)&scsh[kc * 4];
      float4 sh4 = *(const float4*)&scsh[64 + kc * 4];
      v.x = fmaxf(fmaf(v.x, sc4.x, sh4.x), 0.f);
      v.y = fmaxf(fmaf(v.y, sc4.y, sh4.y), 0.f);
      v.z = fmaxf(fmaf(v.z, sc4.z, sh4.z), 0.f);
      v.w = fmaxf(fmaf(v.w, sc4.w, sh4.w), 0.f);
    }
    *(float4*)&aS[r * AST + kc * 4] = v;
  }
  constexpr int WF4 = K * 32;
  for (int i = t; i < WF4; i += 256)
    *(float4*)&wS[i * 4] = *(const float4*)&W[i * 4];
  attS[t] = (t < 128) ? att_s[t] : att_d[t - 128];
  __syncthreads();

  int tc = t & 15, tr = t >> 4;
  int c0 = tc * 8, r0 = tr * 4;

  float acc[4][8] = {};
  for (int k = 0; k < K; k += 4) {
    float4 av[4];
    float4 wv[4][2];
#pragma unroll
    for (int i = 0; i < 4; i++) av[i] = *(const float4*)&aS[(r0 + i) * AST + k];
#pragma unroll
    for (int kk = 0; kk < 4; kk++) {
      wv[kk][0] = *(const float4*)&wS[(k + kk) * 128 + c0];
      wv[kk][1] = *(const float4*)&wS[(k + kk) * 128 + c0 + 4];
    }
#pragma unroll
    for (int i = 0; i < 4; i++) {
      const float* ai = (const float*)&av[i];
#pragma unroll
      for (int kk = 0; kk < 4; kk++) {
        const float* w0 = (const float*)&wv[kk][0];
        const float* w1 = (const float*)&wv[kk][1];
#pragma unroll
        for (int j = 0; j < 4; j++) {
          acc[i][j] = fmaf(ai[kk], w0[j], acc[i][j]);
          acc[i][4 + j] = fmaf(ai[kk], w1[j], acc[i][4 + j]);
        }
      }
    }
  }

#pragma unroll
  for (int i = 0; i < 4; i++) {
    int r = r0 + i;
    float psv = 0.f, pdv = 0.f;
#pragma unroll
    for (int j = 0; j < 8; j++) {
      psv = fmaf(acc[i][j], attS[c0 + j], psv);
      pdv = fmaf(acc[i][j], attS[128 + c0 + j], pdv);
    }
    psv += __shfl_xor(psv, 1); pdv += __shfl_xor(pdv, 1);
    psv += __shfl_xor(psv, 2); pdv += __shfl_xor(pdv, 2);
    psv += __shfl_xor(psv, 4); pdv += __shfl_xor(pdv, 4);
    if (r < rows) {
      size_t base = (size_t)(node0 + r) * 64 + (c0 >> 1);
      hb[base + 0] = __floats2half2_rn(acc[i][0], acc[i][1]);
      hb[base + 1] = __floats2half2_rn(acc[i][2], acc[i][3]);
      hb[base + 2] = __floats2half2_rn(acc[i][4], acc[i][5]);
      hb[base + 3] = __floats2half2_rn(acc[i][6], acc[i][7]);
      if (tc == 0 || tc == 8) {
        int head = tc >> 3;
        as_[(node0 + r) * 2 + head] = psv;
        ad_[(node0 + r) * 2 + head] = pdv;
      }
    }
  }
}

// ---------------- GAT aggregation: wave per node ----------------------------
// 4 edges/group, 16 lanes/edge (sub = lane>>4, q = lane&15, 8 ch/lane).
// Two groups pipelined per iteration. Inline scores (as_ L2-resident).
__device__ __forceinline__ void fma8(float* a, float my, uint4 raw) {
  float2 f;
  f = __half22float2(__builtin_bit_cast(__half2, raw.x)); a[0] = fmaf(my, f.x, a[0]); a[1] = fmaf(my, f.y, a[1]);
  f = __half22float2(__builtin_bit_cast(__half2, raw.y)); a[2] = fmaf(my, f.x, a[2]); a[3] = fmaf(my, f.y, a[3]);
  f = __half22float2(__builtin_bit_cast(__half2, raw.z)); a[4] = fmaf(my, f.x, a[4]); a[5] = fmaf(my, f.y, a[5]);
  f = __half22float2(__builtin_bit_cast(__half2, raw.w)); a[6] = fmaf(my, f.x, a[6]); a[7] = fmaf(my, f.y, a[7]);
}

__global__ __launch_bounds__(256) void gat_aggregate(
    const __half2* __restrict__ hb,
    const float* __restrict__ as_, const float* __restrict__ ad_,
    const int* __restrict__ row_ptr, const int2* __restrict__ col2,
    const float* __restrict__ bias, float* __restrict__ out, int n) {
  int wave = (int)((blockIdx.x * blockDim.x + threadIdx.x) >> 6);
  int lane = threadIdx.x & 63;
  if (wave >= n) return;
  int d = wave;
  int sub = lane >> 4, q = lane & 15;
  bool head1 = (q >= 8);
  int hidx = head1 ? 1 : 0;
  int beg = row_ptr[d], end = row_ptr[d + 1];
  const uint4* hb4 = (const uint4*)hb;   // 16 uint4 per node (256 B)

  float2 dv = *(const float2*)&ad_[d * 2];
  float ad_my = head1 ? dv.y : dv.x;

  float a[8] = {};
  float dpart = 0.f;

  if (sub == 0) {  // self-loop (not in CSR)
    float asv = as_[d * 2 + hidx];
    float my = __expf(leaky(asv + ad_my));
    uint4 raw = hb4[(size_t)d * 16 + q];
    fma8(a, my, raw);
    dpart = my;
  }

  int k = beg;
  for (; k + 7 < end; k += 8) {
    int kkA = k + sub, kkB = k + 4 + sub;
    int sA = col2[kkA].x;
    int sB = col2[kkB].x;
    float asA = as_[sA * 2 + hidx];
    float asB = as_[sB * 2 + hidx];
    uint4 rawA = hb4[(size_t)sA * 16 + q];
    uint4 rawB = hb4[(size_t)sB * 16 + q];
    float myA = __expf(leaky(asA + ad_my));
    float myB = __expf(leaky(asB + ad_my));
    fma8(a, myA, rawA);
    dpart += myA;
    fma8(a, myB, rawB);
    dpart += myB;
  }
  if (k + 3 < end) {
    int kk = k + sub;
    int s = col2[kk].x;
    float asv = as_[s * 2 + hidx];
    uint4 raw = hb4[(size_t)s * 16 + q];
    float my = __expf(leaky(asv + ad_my));
    fma8(a, my, raw);
    dpart += my;
    k += 4;
  }
  int rem = end - k;
  if (sub < rem) {
    int kk = k + sub;
    int s = col2[kk].x;
    float asv = as_[s * 2 + hidx];
    uint4 raw = hb4[(size_t)s * 16 + q];
    float my = __expf(leaky(asv + ad_my));
    fma8(a, my, raw);
    dpart += my;
  }

  // butterfly combine across the 4 sub groups (same q)
#pragma unroll
  for (int i = 0; i < 8; i++) a[i] += __shfl(a[i], lane ^ 16);
  dpart += __shfl(dpart, lane ^ 16);
#pragma unroll
  for (int i = 0; i < 8; i++) a[i] += __shfl(a[i], lane ^ 32);
  float dsum = dpart + __shfl(dpart, lane ^ 32);

  // head-1 values for lane q (<8) live at lane q+8 (same sub group)
  int src = (lane + 8) & 63;
  float b[8];
#pragma unroll
  for (int i = 0; i < 8; i++) b[i] = __shfl(a[i], src);
  float den1 = __shfl(dsum, src);
  if (lane < 8) {  // sub 0, q 0..7: output channels 8q..8q+7
    float r0 = 1.f / (dsum + 1e-16f), r1 = 1.f / (den1 + 1e-16f);
    float4 bl = *(const float4*)&bias[q * 8];
    float4 bh = *(const float4*)&bias[q * 8 + 4];
    float4 o0, o1;
    o0.x = 0.5f * (a[0] * r0 + b[0] * r1) + bl.x;
    o0.y = 0.5f * (a[1] * r0 + b[1] * r1) + bl.y;
    o0.z = 0.5f * (a[2] * r0 + b[2] * r1) + bl.z;
    o0.w = 0.5f * (a[3] * r0 + b[3] * r1) + bl.w;
    o1.x = 0.5f * (a[4] * r0 + b[4] * r1) + bh.x;
    o1.y = 0.5f * (a[5] * r0 + b[5] * r1) + bh.y;
    o1.z = 0.5f * (a[6] * r0 + b[6] * r1) + bh.z;
    o1.w = 0.5f * (a[7] * r0 + b[7] * r1) + bh.w;
    *(float4*)&out[(size_t)d * 64 + q * 8] = o0;
    *(float4*)&out[(size_t)d * 64 + q * 8 + 4] = o1;
  }
}

// ---------------- MLP head: fused tiled GEMM (64 nodes / block) --------------
// a1 staging applies BN(layer3 scsh)+ReLU to the raw aggregate output.
__global__ __launch_bounds__(256) void mlp_head_tiled(
    const float* __restrict__ h3raw, const float* __restrict__ scsh,
    const float* __restrict__ x,
    const float* __restrict__ mW1, const float* __restrict__ mb1,
    const float* __restrict__ mW2, const float* __restrict__ mb2,
    const float* __restrict__ pW, const float* __restrict__ pb,
    const float* __restrict__ vW, const float* __restrict__ vb,
    float* __restrict__ out, int n) {
  __shared__ float lds[13632];
  float* a1  = lds;           // 64*68 = 4352
  float* ctx = lds + 4352;    // 64*8  = 512
  float* a2  = lds + 4864;    // 64*68 = 4352
  float* w1  = lds + 9216;    // 69*64 = 4416
  float* w2  = lds;           // aliases a1 (dead after GEMM1)

  int t = threadIdx.x;
  int node0 = blockIdx.x * 64;
  int rows = min(64, n - node0);

#pragma unroll
  for (int i = 0; i < 4; i++) {
    int flat = t + i * 256;
    int r = flat >> 4, kc = flat & 15;
    float4 v = make_float4(0.f, 0.f, 0.f, 0.f);
    if (r < rows) v = *(const float4*)&h3raw[(size_t)(node0 + r) * 64 + kc * 4];
    float4 sc4 = *(const float4*)&scsh[kc * 4];
    float4 sh4 = *(const float4*)&scsh[64 + kc * 4];
    v.x = fmaxf(fmaf(v.x, sc4.x, sh4.x), 0.f);
    v.y = fmaxf(fmaf(v.y, sc4.y, sh4.y), 0.f);
    v.z = fmaxf(fmaf(v.z, sc4.z, sh4.z), 0.f);
    v.w = fmaxf(fmaf(v.w, sc4.w, sh4.w), 0.f);
    *(float4*)&a1[r * 68 + kc * 4] = v;
  }
  for (int i = t; i < 320; i += 256) {
    int r = i / 5, j = i % 5;
    ctx[r * 8 + j] = (r < rows) ? x[(size_t)(node0 + r) * 16 + 9 + j] : 0.f;
  }
#pragma unroll
  for (int i = 0; i < 5; i++) {
    int flat = t + i * 256;
    if (flat < 1104) *(float4*)&w1[flat * 4] = *(const float4*)&mW1[flat * 4];
  }
  __syncthreads();

  int tc = t & 15, tr = t >> 4;
  int c0 = tc * 4, r0 = tr * 4;

  float acc[4][4] = {};
  for (int k = 0; k < 64; k += 4) {
    float4 av[4], wv[4];
#pragma unroll
    for (int i = 0; i < 4; i++) av[i] = *(const float4*)&a1[(r0 + i) * 68 + k];
#pragma unroll
    for (int j = 0; j < 4; j++) wv[j] = *(const float4*)&w1[(k + j) * 64 + c0];
#pragma unroll
    for (int i = 0; i < 4; i++) {
      const float* ai = (const float*)&av[i];
#pragma unroll
      for (int kk = 0; kk < 4; kk++) {
        const float* wr = (const float*)&wv[kk];
        acc[i][0] = fmaf(ai[kk], wr[0], acc[i][0]);
        acc[i][1] = fmaf(ai[kk], wr[1], acc[i][1]);
        acc[i][2] = fmaf(ai[kk], wr[2], acc[i][2]);
        acc[i][3] = fmaf(ai[kk], wr[3], acc[i][3]);
      }
    }
  }
#pragma unroll
  for (int k = 64; k < 69; k++) {
    float4 wv = *(const float4*)&w1[k * 64 + c0];
    const float* wr = (const float*)&wv;
#pragma unroll
    for (int i = 0; i < 4; i++) {
      float a = ctx[(r0 + i) * 8 + (k - 64)];
      acc[i][0] = fmaf(a, wr[0], acc[i][0]);
      acc[i][1] = fmaf(a, wr[1], acc[i][1]);
      acc[i][2] = fmaf(a, wr[2], acc[i][2]);
      acc[i][3] = fmaf(a, wr[3], acc[i][3]);
    }
  }
  float b1v0 = mb1[c0], b1v1 = mb1[c0 + 1], b1v2 = mb1[c0 + 2], b1v3 = mb1[c0 + 3];
#pragma unroll
  for (int i = 0; i < 4; i++) {
    float4 t1;
    t1.x = fmaxf(acc[i][0] + b1v0, 0.f);
    t1.y = fmaxf(acc[i][1] + b1v1, 0.f);
    t1.z = fmaxf(acc[i][2] + b1v2, 0.f);
    t1.w = fmaxf(acc[i][3] + b1v3, 0.f);
    *(float4*)&a2[(r0 + i) * 68 + c0] = t1;
  }
  __syncthreads();

#pragma unroll
  for (int i = 0; i < 4; i++) {
    int flat = t + i * 256;
    *(float4*)&w2[flat * 4] = *(const float4*)&mW2[flat * 4];
  }
  __syncthreads();

  float acc2[4][4] = {};
  for (int k = 0; k < 64; k += 4) {
    float4 av[4], wv[4];
#pragma unroll
    for (int i = 0; i < 4; i++) av[i] = *(const float4*)&a2[(r0 + i) * 68 + k];
#pragma unroll
    for (int j = 0; j < 4; j++) wv[j] = *(const float4*)&w2[(k + j) * 64 + c0];
#pragma unroll
    for (int i = 0; i < 4; i++) {
      const float* ai = (const float*)&av[i];
#pragma unroll
      for (int kk = 0; kk < 4; kk++) {
        const float* wr = (const float*)&wv[kk];
        acc2[i][0] = fmaf(ai[kk], wr[0], acc2[i][0]);
        acc2[i][1] = fmaf(ai[kk], wr[1], acc2[i][1]);
        acc2[i][2] = fmaf(ai[kk], wr[2], acc2[i][2]);
        acc2[i][3] = fmaf(ai[kk], wr[3], acc2[i][3]);
      }
    }
  }

  float b2v[4], pwv[4], vwv[4];
#pragma unroll
  for (int j = 0; j < 4; j++) {
    b2v[j] = mb2[c0 + j];
    pwv[j] = pW[c0 + j];
    vwv[j] = vW[c0 + j];
  }
  float p[4], v[4];
#pragma unroll
  for (int i = 0; i < 4; i++) {
    float ps = 0.f, vs = 0.f;
#pragma unroll
    for (int j = 0; j < 4; j++) {
      float u = acc2[i][j] + b2v[j];
      ps = fmaf(u, pwv[j], ps);
      vs = fmaf(u, vwv[j], vs);
    }
    p[i] = ps; v[i] = vs;
  }
#pragma unroll
  for (int off = 1; off < 16; off <<= 1) {
#pragma unroll
    for (int i = 0; i < 4; i++) {
      p[i] += __shfl_xor(p[i], off);
      v[i] += __shfl_xor(v[i], off);
    }
  }
  if (tc == 0) {
    float pbs = pb[0], vbs = vb[0];
#pragma unroll
    for (int i = 0; i < 4; i++) {
      int r = r0 + i;
      if (r < rows) {
        out[node0 + r] = p[i] + pbs;
        out[n + node0 + r] = v[i] + vbs;
      }
    }
  }
}

extern "C" void kernel_launch(void* const* d_in, const int* in_sizes, int n_in,
                              void* d_out, int out_size, void* d_ws, size_t ws_size,
                              hipStream_t stream) {
  const float* x = (const float*)d_in[0];
  const int* ei = (const int*)d_in[1];
  const float* W[3]  = {(const float*)d_in[2],  (const float*)d_in[8],  (const float*)d_in[14]};
  const float* AS[3] = {(const float*)d_in[3],  (const float*)d_in[9],  (const float*)d_in[15]};
  const float* AD[3] = {(const float*)d_in[4],  (const float*)d_in[10], (const float*)d_in[16]};
  const float* B[3]  = {(const float*)d_in[5],  (const float*)d_in[11], (const float*)d_in[17]};
  const float* G[3]  = {(const float*)d_in[6],  (const float*)d_in[12], (const float*)d_in[18]};
  const float* BE[3] = {(const float*)d_in[7],  (const float*)d_in[13], (const float*)d_in[19]};
  const float* mW1 = (const float*)d_in[20];
  const float* mb1 = (const float*)d_in[21];
  const float* mW2 = (const float*)d_in[22];
  const float* mb2 = (const float*)d_in[23];
  const float* pW  = (const float*)d_in[24];
  const float* pb  = (const float*)d_in[25];
  const float* vW  = (const float*)d_in[26];
  const float* vb  = (const float*)d_in[27];

  const int N = in_sizes[0] / 16;
  const int E = in_sizes[1] / 2;
  const int* srcp = ei;
  const int* dstp = ei + E;

  // workspace carve-up (~70 MB)
  float* bufB  = (float*)d_ws;               // N*64  raw aggregate output
  float* hbuf  = bufB + (size_t)N * 64;      // N*64 half2 region (N*64 f32 bytes)
  float* as_   = hbuf + (size_t)N * 64;      // N*2
  float* ad_   = as_ + (size_t)N * 2;        // N*2
  float* stats = ad_ + (size_t)N * 2;        // NSL*128
  float* scsh  = stats + NSL * 128;          // 128
  int* row_ptr = (int*)(scsh + 128);         // N+1
  int* bcnt    = row_ptr + (N + 1);          // 512
  int* boff    = bcnt + 512;                 // 512
  int* bcur    = boff + 512;                 // 512
  int2* col2   = (int2*)(bcur + 512);        // E int2 (sorted CSR)
  int2* ebuf   = col2 + E;                   // E int2 (staging)
  __half2* hb  = (__half2*)hbuf;

  const int nbk = (N + 255) >> 8;
  const float inv_n = 1.0f / (float)N;

  // ---- CSR build: binned counting sort (R17 formulation)
  hipMemsetAsync(bcnt, 0, sizeof(int) * 512, stream);
  bucket_hist<<<256, 256, 0, stream>>>(dstp, bcnt, E);
  bucket_scan<<<1, 512, 0, stream>>>(bcnt, boff, bcur, nbk);
  bin_scatter<<<(E + 8191) / 8192, 256, 0, stream>>>(srcp, dstp, bcur, ebuf, E);
  bucket_sort<<<nbk, 256, 0, stream>>>(ebuf, boff, col2, row_ptr, E, N, nbk);

  const int tiles = (N + 63) / 64;

  // ---- 3 GAT layers (BN+ReLU fused into the next consumer via scsh)
  for (int l = 0; l < 3; l++) {
    if (l == 0)
      gat_project_tiled<16, false><<<tiles, 256, 0, stream>>>(x, scsh, W[l], AS[l], AD[l],
                                                              hb, as_, ad_, N);
    else
      gat_project_tiled<64, true><<<tiles, 256, 0, stream>>>(bufB, scsh, W[l], AS[l], AD[l],
                                                             hb, as_, ad_, N);
    gat_aggregate<<<(N + 3) / 4, 256, 0, stream>>>(hb, as_, ad_, row_ptr, col2,
                                                   B[l], bufB, N);
    bn_stats<<<NSL, 256, 0, stream>>>(bufB, stats, N);
    bn_finalize<<<1, 128, 0, stream>>>(stats, G[l], BE[l], scsh, inv_n);
  }

  // ---- MLP head -> (logits, value); applies layer-3 BN+ReLU to bufB
  mlp_head_tiled<<<tiles, 256, 0, stream>>>(bufB, scsh, x, mW1, mb1, mW2, mb2,
                                            pW, pb, vW, vb, (float*)d_out, N);
}